// Round 3
// baseline (412.701 us; speedup 1.0000x reference)
//
#include <hip/hip_runtime.h>
#include <hip/hip_bf16.h>

#define BN 262144
#define LNUM 15

// ---- setup: compose permutations into cumulative index maps c[l][16] ----
// logical x[j] at layer l lives at physical slot c[l][j]; c[l+1][j] = c[l][perm_l[j]]
extern "C" __global__ void compose_perms(const int* __restrict__ perms, int* __restrict__ c) {
    if (threadIdx.x != 0 || blockIdx.x != 0) return;
    int cur[16];
    for (int j = 0; j < 16; ++j) { cur[j] = j; c[j] = j; }
    for (int l = 0; l < LNUM; ++l) {
        int nx[16];
        for (int j = 0; j < 16; ++j) nx[j] = cur[perms[l * 16 + j]];
        for (int j = 0; j < 16; ++j) { c[(l + 1) * 16 + j] = nx[j]; cur[j] = nx[j]; }
    }
}

// out[o] = b[o] + sum_i in[i] * W[i][o]  (bias folded into first FMA row)
__device__ __forceinline__ void matvec8(const float in[8],
                                        const float* __restrict__ W,
                                        const float* __restrict__ b,
                                        float out[8]) {
#pragma unroll
    for (int o = 0; o < 8; ++o) out[o] = fmaf(in[0], W[o], b[o]);
#pragma unroll
    for (int ii = 1; ii < 8; ++ii) {
        float xv = in[ii];
#pragma unroll
        for (int o = 0; o < 8; ++o) out[o] = fmaf(xv, W[ii * 8 + o], out[o]);
    }
}

__device__ __forceinline__ void lrelu8(float v[8]) {
#pragma unroll
    for (int o = 0; o < 8; ++o) v[o] = fmaxf(v[o], 0.01f * v[o]);
}

__device__ __forceinline__ void mlp8(const float in[8],
                                     const float* __restrict__ Wi, const float* __restrict__ bi,
                                     const float* __restrict__ Wh, const float* __restrict__ bh,
                                     const float* __restrict__ Wo, const float* __restrict__ bo,
                                     float out[8]) {
    float h[8], g[8];
    matvec8(in, Wi, bi, h);
    lrelu8(h);
#pragma unroll
    for (int j = 0; j < 3; ++j) {
        matvec8(h, Wh + j * 64, bh + j * 8, g);
        lrelu8(g);
#pragma unroll
        for (int k = 0; k < 8; ++k) h[k] = g[k];
    }
    matvec8(h, Wo, bo, out);
}

// 2 threads per sample: wave parity = role (0: log_s net, 1: b net).
// x lives un-permuted in a shared per-sample LDS slot; composed perms index it.
extern "C" __global__ void __launch_bounds__(256) flow_fwd(
    const float* __restrict__ z,
    const float* __restrict__ Wi, const float* __restrict__ bi,
    const float* __restrict__ Wh, const float* __restrict__ bh,
    const float* __restrict__ Wo, const float* __restrict__ bo,
    const int* __restrict__ cperm,
    float* __restrict__ outy, float* __restrict__ outld) {
    // slot: [0:16] x(physical), [17:25] s-net out, [25:33] b-net out. stride 33 (odd -> 2-way banks, free)
    __shared__ float xs[128 * 33];
    const int t = threadIdx.x;
    const int wave = t >> 6, lane = t & 63;
    const int r = wave & 1;         // role: 0 = log_s net, 1 = b net
    const int pairIdx = wave >> 1;  // 0..1
    const int slot = pairIdx * 64 + lane;
    const long samp = (long)blockIdx.x * 128 + slot;
    float* __restrict__ sx = &xs[slot * 33];

    // init: each role loads/stores its half of the row (dedup global + LDS traffic)
    {
        const float4* zp = reinterpret_cast<const float4*>(z + samp * 16 + r * 8);
        float4 a0 = zp[0], a1 = zp[1];
        float* xi = sx + r * 8;
        xi[0] = a0.x; xi[1] = a0.y; xi[2] = a0.z; xi[3] = a0.w;
        xi[4] = a1.x; xi[5] = a1.y; xi[6] = a1.z; xi[7] = a1.w;
    }
    float ld = 0.f;
    __syncthreads();

    for (int l = 0; l < LNUM; ++l) {
        const int* __restrict__ cl = cperm + l * 16;
        // read z_l through composed permutation (uniform scalar offsets)
        float in[8];
#pragma unroll
        for (int j = 0; j < 8; ++j) in[j] = sx[cl[j]];

        const int idx = l * 2 + r;  // wave-uniform -> weight loads scalarize
        float o[8];
        mlp8(in, Wi + idx * 64, bi + idx * 8, Wh + idx * 192, bh + idx * 24,
             Wo + idx * 64, bo + idx * 8, o);

        // exchange with partner wave via LDS
        {
            float* em = sx + 17 + r * 8;
#pragma unroll
            for (int k = 0; k < 8; ++k) em[k] = o[k];
        }
        __syncthreads();
        float p[8];
        {
            const float* eo = sx + 17 + (1 - r) * 8;
#pragma unroll
            for (int k = 0; k < 8; ++k) p[k] = eo[k];
        }

        // both roles clip s (r==0: own = s ; r==1: partner = s)
        float cs[8];
#pragma unroll
        for (int k = 0; k < 8; ++k) {
            float s_ = r ? p[k] : o[k];
            cs[k] = fminf(fmaxf(s_, -5.f), 5.f);
        }
        if (r == 0) {
#pragma unroll
            for (int k = 0; k < 8; ++k) ld += cs[k];
        }
        // my half of the affine update: k in [r*4, r*4+4)  (disjoint physical slots)
#pragma unroll
        for (int k2 = 0; k2 < 4; ++k2) {
            const int k = r * 4 + k2;
            const float bvk = r ? o[k] : p[k];
            const float tt = __expf(cs[k]) + 1e-6f;
            const int ph = cl[8 + k];
            sx[ph] = tt * sx[ph] + bvk;
        }
        __syncthreads();
    }

    // final: read through c[15], each role stores its 8 columns (2 float4s)
    const int* __restrict__ cf = cperm + LNUM * 16;
    const int jb = r * 8;
    float4 q0, q1;
    q0.x = sx[cf[jb + 0]]; q0.y = sx[cf[jb + 1]]; q0.z = sx[cf[jb + 2]]; q0.w = sx[cf[jb + 3]];
    q1.x = sx[cf[jb + 4]]; q1.y = sx[cf[jb + 5]]; q1.z = sx[cf[jb + 6]]; q1.w = sx[cf[jb + 7]];
    float4* yrow = reinterpret_cast<float4*>(outy + samp * 16);
    yrow[r * 2 + 0] = q0;
    yrow[r * 2 + 1] = q1;
    if (r == 0) outld[samp] = ld;
}

extern "C" void kernel_launch(void* const* d_in, const int* in_sizes, int n_in,
                              void* d_out, int out_size, void* d_ws, size_t ws_size,
                              hipStream_t stream) {
    const float* z = (const float*)d_in[0];
    const float* Wi = (const float*)d_in[1];
    const float* bi = (const float*)d_in[2];
    const float* Wh = (const float*)d_in[3];
    const float* bh = (const float*)d_in[4];
    const float* Wo = (const float*)d_in[5];
    const float* bo = (const float*)d_in[6];
    const int* perms = (const int*)d_in[7];
    float* out = (float*)d_out;
    int* cperm = (int*)d_ws;  // (LNUM+1) x 16 ints

    hipLaunchKernelGGL(compose_perms, dim3(1), dim3(64), 0, stream, perms, cperm);
    dim3 grid(BN / 128), block(256);
    hipLaunchKernelGGL(flow_fwd, grid, block, 0, stream,
                       z, Wi, bi, Wh, bh, Wo, bo, cperm, out, out + (size_t)BN * 16);
}

// Round 4
// 147.750 us; speedup vs baseline: 2.7932x; 2.7932x over previous
//
#include <hip/hip_runtime.h>
#include <hip/hip_bf16.h>

#define BN 262144
#define LNUM 15

// ---- setup: compose permutations into cumulative index maps c[l][16] ----
// logical x[j] at layer l lives at physical slot c[l][j]; c[l+1][j] = c[l][perm_l[j]]
extern "C" __global__ void compose_perms(const int* __restrict__ perms, int* __restrict__ c) {
    if (threadIdx.x != 0 || blockIdx.x != 0) return;
    int cur[16];
    for (int j = 0; j < 16; ++j) { cur[j] = j; c[j] = j; }
    for (int l = 0; l < LNUM; ++l) {
        int nx[16];
        for (int j = 0; j < 16; ++j) nx[j] = cur[perms[l * 16 + j]];
        for (int j = 0; j < 16; ++j) { c[(l + 1) * 16 + j] = nx[j]; cur[j] = nx[j]; }
    }
}

// out[o] = b[o] + sum_i in[i] * W[i][o]  (bias folded into first FMA row)
__device__ __forceinline__ void matvec8(const float in[8],
                                        const float* __restrict__ W,
                                        const float* __restrict__ b,
                                        float out[8]) {
#pragma unroll
    for (int o = 0; o < 8; ++o) out[o] = fmaf(in[0], W[o], b[o]);
#pragma unroll
    for (int ii = 1; ii < 8; ++ii) {
        float xv = in[ii];
#pragma unroll
        for (int o = 0; o < 8; ++o) out[o] = fmaf(xv, W[ii * 8 + o], out[o]);
    }
}

__device__ __forceinline__ void lrelu8(float v[8]) {
#pragma unroll
    for (int o = 0; o < 8; ++o) v[o] = fmaxf(v[o], 0.01f * v[o]);
}

__device__ __forceinline__ void mlp8(const float in[8],
                                     const float* __restrict__ Wi, const float* __restrict__ bi,
                                     const float* __restrict__ Wh, const float* __restrict__ bh,
                                     const float* __restrict__ Wo, const float* __restrict__ bo,
                                     float out[8]) {
    float h[8], g[8];
    matvec8(in, Wi, bi, h);
    lrelu8(h);
#pragma unroll
    for (int j = 0; j < 3; ++j) {
        matvec8(h, Wh + j * 64, bh + j * 8, g);
        lrelu8(g);
#pragma unroll
        for (int k = 0; k < 8; ++k) h[k] = g[k];
    }
    matvec8(h, Wo, bo, out);
}

// 2 threads per sample: wave parity = role (0: log_s net, 1: b net).
// x lives un-permuted in a shared per-sample LDS slot; composed perms index it.
// Weight index is hoisted to SGPR via readfirstlane so weight loads scalarize.
extern "C" __global__ void __launch_bounds__(256, 8) flow_fwd(
    const float* __restrict__ z,
    const float* __restrict__ Wi, const float* __restrict__ bi,
    const float* __restrict__ Wh, const float* __restrict__ bh,
    const float* __restrict__ Wo, const float* __restrict__ bo,
    const int* __restrict__ cperm,
    float* __restrict__ outy, float* __restrict__ outld) {
    // slot: [0:16] x(physical), [17:25] s-net out, [25:33] b-net out. stride 33 (odd -> 2-way banks, free)
    __shared__ float xs[128 * 33];
    const int t = threadIdx.x;
    const int wave = t >> 6, lane = t & 63;
    const int r = wave & 1;         // role: 0 = log_s net, 1 = b net
    // wave-uniform role, hoisted to SGPR so the compiler can prove weight
    // addresses uniform -> s_load (round-3 regression was VMEM weight loads)
    const int rs = __builtin_amdgcn_readfirstlane(r);
    const int pairIdx = wave >> 1;  // 0..1
    const int slot = pairIdx * 64 + lane;
    const long samp = (long)blockIdx.x * 128 + slot;
    float* __restrict__ sx = &xs[slot * 33];

    // init: each role loads/stores its half of the row (dedup global + LDS traffic)
    {
        const float4* zp = reinterpret_cast<const float4*>(z + samp * 16 + r * 8);
        float4 a0 = zp[0], a1 = zp[1];
        float* xi = sx + r * 8;
        xi[0] = a0.x; xi[1] = a0.y; xi[2] = a0.z; xi[3] = a0.w;
        xi[4] = a1.x; xi[5] = a1.y; xi[6] = a1.z; xi[7] = a1.w;
    }
    float ld = 0.f;
    __syncthreads();

    for (int l = 0; l < LNUM; ++l) {
        const int* __restrict__ cl = cperm + l * 16;
        // read z_l through composed permutation (uniform scalar offsets)
        float in[8];
#pragma unroll
        for (int j = 0; j < 8; ++j) in[j] = sx[cl[j]];

        const int idx = l * 2 + rs;  // SGPR-uniform -> weight loads scalarize
        float o[8];
        mlp8(in, Wi + idx * 64, bi + idx * 8, Wh + idx * 192, bh + idx * 24,
             Wo + idx * 64, bo + idx * 8, o);

        // exchange with partner wave via LDS
        {
            float* em = sx + 17 + r * 8;
#pragma unroll
            for (int k = 0; k < 8; ++k) em[k] = o[k];
        }
        __syncthreads();
        float p[8];
        {
            const float* eo = sx + 17 + (1 - r) * 8;
#pragma unroll
            for (int k = 0; k < 8; ++k) p[k] = eo[k];
        }

        // both roles clip s (r==0: own = s ; r==1: partner = s)
        float cs[8];
#pragma unroll
        for (int k = 0; k < 8; ++k) {
            float s_ = r ? p[k] : o[k];
            cs[k] = fminf(fmaxf(s_, -5.f), 5.f);
        }
        if (r == 0) {
#pragma unroll
            for (int k = 0; k < 8; ++k) ld += cs[k];
        }
        // my half of the affine update: k in [r*4, r*4+4)  (disjoint physical slots)
#pragma unroll
        for (int k2 = 0; k2 < 4; ++k2) {
            const int k = r * 4 + k2;
            const float bvk = r ? o[k] : p[k];
            const float tt = __expf(cs[k]) + 1e-6f;
            const int ph = cl[8 + k];
            sx[ph] = tt * sx[ph] + bvk;
        }
        __syncthreads();
    }

    // final: read through c[15], each role stores its 8 columns (2 float4s)
    const int* __restrict__ cf = cperm + LNUM * 16;
    const int jb = r * 8;
    float4 q0, q1;
    q0.x = sx[cf[jb + 0]]; q0.y = sx[cf[jb + 1]]; q0.z = sx[cf[jb + 2]]; q0.w = sx[cf[jb + 3]];
    q1.x = sx[cf[jb + 4]]; q1.y = sx[cf[jb + 5]]; q1.z = sx[cf[jb + 6]]; q1.w = sx[cf[jb + 7]];
    float4* yrow = reinterpret_cast<float4*>(outy + samp * 16);
    yrow[r * 2 + 0] = q0;
    yrow[r * 2 + 1] = q1;
    if (r == 0) outld[samp] = ld;
}

extern "C" void kernel_launch(void* const* d_in, const int* in_sizes, int n_in,
                              void* d_out, int out_size, void* d_ws, size_t ws_size,
                              hipStream_t stream) {
    const float* z = (const float*)d_in[0];
    const float* Wi = (const float*)d_in[1];
    const float* bi = (const float*)d_in[2];
    const float* Wh = (const float*)d_in[3];
    const float* bh = (const float*)d_in[4];
    const float* Wo = (const float*)d_in[5];
    const float* bo = (const float*)d_in[6];
    const int* perms = (const int*)d_in[7];
    float* out = (float*)d_out;
    int* cperm = (int*)d_ws;  // (LNUM+1) x 16 ints

    hipLaunchKernelGGL(compose_perms, dim3(1), dim3(64), 0, stream, perms, cperm);
    dim3 grid(BN / 128), block(256);
    hipLaunchKernelGGL(flow_fwd, grid, block, 0, stream,
                       z, Wi, bi, Wh, bh, Wo, bo, cperm, out, out + (size_t)BN * 16);
}